// Round 13
// baseline (190.736 us; speedup 1.0000x reference)
//
#include <hip/hip_runtime.h>

#define BATCH 32
#define NCAPS 32
#define NR    4608
#define NI    8
#define NO    16
#define NOH   8      // o per block (o-split across 2 blocks per chunk)
// CSTR8 = 104 floats (416B) per capsule row (8 o x 12 + 8 slack): 16B-aligned rows
// -> ds_read_b128; 104 = 8 mod 32 and 8*104 = 0 mod 32 -> same bank decorrelation
// as R10's CSTR=200 with slot permutation sigma(c) = (c>>2) + 8*(c&3):
// read start bank = (8co + 12*o_loc + 4seg) mod 32; each aligned 8-lane phase
// (4 om x 2 co1) hits {0,12,24,4}+{0,16} = 8 distinct bank-quads. Conflict-free.
#define CSTR8 104
#define CSTR  200    // generic fallback keeps the R6 layout
#define MAXRB 36
#define NCH   256    // chunks; grid = 2*NCH (o-split) -> 2 blocks/CU co-resident
#define L2E   1.44269504088896341f

typedef float f2 __attribute__((ext_vector_type(2)));

// ---------------- fast path ----------------
// Grid 512 = 256 chunks x 2 o-halves; 1024 threads; LDS ~74KB -> 2 blocks/CU
// (2048 threads, 8 waves/SIMD) with RB=18 amortization kept. Thread = b-pair
// (bp = t>>6, wave-uniform) x 4 c (co octant) x 1 o. Inner math = R10's proven
// loop. 1 barrier per 2 r (R12's supertile double-buffer).
template<int RB, bool FIRST>
__global__ __launch_bounds__(1024, 8) void caps_route_fast(
    const float* __restrict__ x,    // [B][R][I]
    const float* __restrict__ W,    // [C][R][I][O]
    const float* __restrict__ A,    // [B][C][O]
    float* __restrict__ P)          // [NCH][B][O][C]
{
    constexpr int NP = RB / 2;                              // supertiles (9)
    __shared__ __align__(16) float Ws[2][2][NCAPS * CSTR8]; // 53.2 KB
    __shared__ __align__(16) f2    xP[RB][16][NI + 1];      // 20.7 KB

    const int t  = threadIdx.x;
    // lane-bit scramble (om in bits 0,1,3; co in bits 2,4,5) -> conflict-free b128.
    const int om = (t & 3) | (((t >> 3) & 1) << 2);
    const int co = ((t >> 4) & 1) | (((t >> 2) & 1) << 1) | (((t >> 5) & 1) << 2);
    const int bp = t >> 6;            // wave id = b pair (16 waves)
    const int b0 = 2 * bp;
    const int chunk = blockIdx.x >> 1;
    const int oh8   = (blockIdx.x & 1) * NOH;
    const int o     = oh8 + om;       // global o
    const int r0    = chunk * RB;

    f2 a2[4];
    if (!FIRST) {
#pragma unroll
        for (int cl = 0; cl < 4; ++cl) {
            const int c = 4 * co + cl;
            a2[cl].x = A[((b0 + 0) * NCAPS + c) * NO + o] * L2E;
            a2[cl].y = A[((b0 + 1) * NCAPS + c) * NO + o] * L2E;
        }
    }
    f2 acc[4];
#pragma unroll
    for (int cl = 0; cl < 4; ++cl) acc[cl] = (f2)0.f;

    // Stage x pre-interleaved: xP[rr][bq][i] = {x[2bq][i], x[2bq+1][i]}.
    for (int s = t; s < RB * 16; s += 1024) {
        const int rr = s >> 4, bq = s & 15;
        const float* xp0 = &x[((size_t)(2 * bq + 0) * NR + r0 + rr) * NI];
        const float* xp1 = &x[((size_t)(2 * bq + 1) * NR + r0 + rr) * NI];
        const float4 a0 = *(const float4*)xp0;
        const float4 a1 = *(const float4*)(xp0 + 4);
        const float4 c0 = *(const float4*)xp1;
        const float4 c1 = *(const float4*)(xp1 + 4);
        f2* d = &xP[rr][bq][0];
        d[0] = f2{a0.x, c0.x}; d[1] = f2{a0.y, c0.y};
        d[2] = f2{a0.z, c0.z}; d[3] = f2{a0.w, c0.w};
        d[4] = f2{a1.x, c1.x}; d[5] = f2{a1.y, c1.y};
        d[6] = f2{a1.z, c1.z}; d[7] = f2{a1.w, c1.w};
    }

    // W staging: thread owns (c_st, sub_r, i_st, oq): one float4 (4 o_loc at
    // fixed i) per supertile; capsule c_st lands in slot sigma = (c>>2)+8*(c&3).
    const int c_st  = t >> 5;
    const int sl    = (c_st >> 2) + 8 * (c_st & 3);
    const int part  = t & 31;
    const int sub_r = part >> 4;
    const int i_st  = (part >> 1) & 7;
    const int oq    = part & 1;
    const float* wsrc = W + ((size_t)c_st * NR + r0 + sub_r) * (NI * NO)
                          + i_st * NO + oh8 + oq * 4;
    const int dst = sl * CSTR8 + oq * 48 + i_st;

    // Prologue: stage supertile 0; prefetch supertile 1.
    {
        const float4 s0 = *(const float4*)wsrc;
        float* d = &Ws[0][sub_r][dst];
        d[0] = s0.x; d[12] = s0.y; d[24] = s0.z; d[36] = s0.w;
    }
    float4 pf = {};
    if (NP > 1) pf = *(const float4*)(wsrc + 2 * NI * NO);
    __syncthreads();

    // Per-r compute: capsule 4co+cl at slot co+8cl; row offset o_loc*12.
    auto compute_r = [&](const float* wt, const f2* xv) {
        f2 xq[NI];
#pragma unroll
        for (int i = 0; i < NI; ++i) xq[i] = xv[i];
        const float* wb = wt + co * CSTR8 + om * 12;
        if (FIRST) {
#pragma unroll
            for (int cl = 0; cl < 4; ++cl) {
                const float* wp = wb + cl * (8 * CSTR8);
                const float4 w0 = *(const float4*)wp;
                const float4 w1 = *(const float4*)(wp + 4);
                f2 u2 = xq[0] * w0.x;
                u2 += xq[1] * w0.y;
                u2 += xq[2] * w0.z;
                u2 += xq[3] * w0.w;
                u2 += xq[4] * w1.x;
                u2 += xq[5] * w1.y;
                u2 += xq[6] * w1.z;
                u2 += xq[7] * w1.w;
                acc[cl] += u2;
            }
        } else {
            f2 tt[4];
            f2 Z = (f2)0.f;
#pragma unroll
            for (int cl = 0; cl < 4; ++cl) {
                const float* wp = wb + cl * (8 * CSTR8);
                const float4 w0 = *(const float4*)wp;
                const float4 w1 = *(const float4*)(wp + 4);
                f2 u2 = xq[0] * w0.x;
                u2 += xq[1] * w0.y;
                u2 += xq[2] * w0.z;
                u2 += xq[3] * w0.w;
                u2 += xq[4] * w1.x;
                u2 += xq[5] * w1.y;
                u2 += xq[6] * w1.z;
                u2 += xq[7] * w1.w;
                // logits bounded (|A|<=3, |u|<~15): exp2 safe without max-sub
                // (validated absmax<=2e-3 through R12).
                const f2 l2 = u2 * a2[cl];
                f2 e2;
                e2.x = exp2f(l2.x);
                e2.y = exp2f(l2.y);
                Z += e2;
                tt[cl] = e2 * u2;
            }
            // Z over 32 c: co lives in lane bits {2,4,5} -> xor 4,16,32.
            Z.x += __shfl_xor(Z.x, 4);  Z.y += __shfl_xor(Z.y, 4);
            Z.x += __shfl_xor(Z.x, 16); Z.y += __shfl_xor(Z.y, 16);
            Z.x += __shfl_xor(Z.x, 32); Z.y += __shfl_xor(Z.y, 32);
            f2 rz;
            rz.x = __builtin_amdgcn_rcpf(Z.x);
            rz.y = __builtin_amdgcn_rcpf(Z.y);
#pragma unroll
            for (int cl = 0; cl < 4; ++cl)
                acc[cl] += tt[cl] * rz;
        }
    };

#pragma unroll 1
    for (int rp = 0; rp < NP; ++rp) {
        const int cur = rp & 1;
        // Stage next supertile into the other buffer; prefetch rp+2.
        if (rp + 1 < NP) {
            float* d = &Ws[cur ^ 1][sub_r][dst];
            d[0] = pf.x; d[12] = pf.y; d[24] = pf.z; d[36] = pf.w;
            if (rp + 2 < NP)
                pf = *(const float4*)(wsrc + (size_t)(2 * rp + 4) * (NI * NO));
        }
        compute_r(&Ws[cur][0][0], &xP[2 * rp + 0][bp][0]);
        compute_r(&Ws[cur][1][0], &xP[2 * rp + 1][bp][0]);
        __syncthreads();
    }

    // Epilogue: P[chunk][b][o][4co..4co+3] for both b's (full 128B lines/wave).
#pragma unroll
    for (int bb = 0; bb < 2; ++bb) {
        float* pout = P + (((size_t)chunk * BATCH + b0 + bb) * NO + o) * NCAPS + 4 * co;
        float4 v;
        v.x = bb ? acc[0].y : acc[0].x;
        v.y = bb ? acc[1].y : acc[1].x;
        v.z = bb ? acc[2].y : acc[2].x;
        v.w = bb ? acc[3].y : acc[3].x;
        if (FIRST) { v.x *= 0.03125f; v.y *= 0.03125f; v.z *= 0.03125f; v.w *= 0.03125f; }
        *(float4*)pout = v;
    }
}

// Stage-1 reduce: coalesced float4 column sums of P[256][16384] -> P2[16][16384].
__global__ __launch_bounds__(256) void caps_partial(const float* __restrict__ P,
                                                    float* __restrict__ P2)
{
    const int tid = threadIdx.x;
    const int ct  = blockIdx.x & 15;
    const int rg  = blockIdx.x >> 4;
    const size_t col = (size_t)ct * 1024 + tid * 4;
    const float* p = P + (size_t)rg * 16 * 16384 + col;
    float4 s = {0.f, 0.f, 0.f, 0.f};
#pragma unroll
    for (int k = 0; k < 16; ++k) {
        const float4 v = *(const float4*)(p + (size_t)k * 16384);
        s.x += v.x; s.y += v.y; s.z += v.z; s.w += v.w;
    }
    *(float4*)(P2 + (size_t)rg * 16384 + col) = s;
}

// Reduce partials over chunks, squash, update A; emit V on the final iteration.
// P layout [chunk][b][o][c].
__global__ void caps_reduce_squash(const float* __restrict__ P,
                                   float* __restrict__ A,
                                   float* __restrict__ out,
                                   int nchunk)
{
    __shared__ float sm[256];
    const int bc  = blockIdx.x;
    const int b   = bc >> 5;
    const int c   = bc & 31;
    const int tid = threadIdx.x;
    const int o = tid & 15;
    const int j = tid >> 4;
    float s = 0.f;
    for (int tch = j; tch < nchunk; tch += 16)
        s += P[(((size_t)tch * BATCH + b) * NO + o) * NCAPS + c];
    sm[tid] = s;
    __syncthreads();
    if (tid < 16) {
        float S = 0.f;
#pragma unroll
        for (int k = 0; k < 16; ++k) S += sm[tid + 16 * k];
        float sq = S * S;
#pragma unroll
        for (int d = 8; d >= 1; d >>= 1) sq += __shfl_xor(sq, d, 16);
        const float scale = sq / ((1.f + sq) * sqrtf(sq));
        const float V = S * scale;
        const int idx = bc * NO + tid;
        A[idx] += V;
        if (out) out[idx] = V;
    }
}

// ---------------- generic fallback (R6 structure, validated) ----------------
__global__ __launch_bounds__(512, 2) void caps_route_generic(
    const float* __restrict__ x, const float* __restrict__ W,
    const float* __restrict__ A, float* __restrict__ P, int rb)
{
    __shared__ __align__(16) float Ws[NCAPS * CSTR];
    __shared__ __align__(16) float xsT[NI * MAXRB * BATCH];

    const int t = threadIdx.x;
    const int b = t & 31;
    const int o = t >> 5;
    const int r0 = blockIdx.x * rb;
    const int rbs = rb * BATCH;

    float a2s[NCAPS];
#pragma unroll
    for (int c = 0; c < NCAPS; ++c)
        a2s[c] = A[(b * NCAPS + c) * NO + o] * L2E;
    float acc[NCAPS];
#pragma unroll
    for (int c = 0; c < NCAPS; ++c) acc[c] = 0.f;

    for (int s = t; s < rbs; s += 512) {
        const int rr = s >> 5, bb = s & 31;
        const float4 v0 = *(const float4*)&x[((size_t)bb * NR + r0 + rr) * NI];
        const float4 v1 = *(const float4*)&x[((size_t)bb * NR + r0 + rr) * NI + 4];
        const float tmp[8] = {v0.x, v0.y, v0.z, v0.w, v1.x, v1.y, v1.z, v1.w};
#pragma unroll
        for (int i = 0; i < NI; ++i) xsT[i * rbs + s] = tmp[i];
    }

    const int cs  = t >> 4;
    const int seg = t & 15;
    const int iw  = seg >> 1;
    const int ob  = (seg & 1) * 8;
    const float* wsrc = W + ((size_t)cs * NR + r0) * (NI * NO) + seg * 8;
    float4 pf0 = *(const float4*)wsrc;
    float4 pf1 = *(const float4*)(wsrc + 4);

    for (int rr = 0; rr < rb; ++rr) {
        __syncthreads();
        {
            const float tmp[8] = {pf0.x, pf0.y, pf0.z, pf0.w,
                                  pf1.x, pf1.y, pf1.z, pf1.w};
#pragma unroll
            for (int k = 0; k < 8; ++k)
                Ws[cs * CSTR + (ob + k) * 12 + iw] = tmp[k];
        }
        if (rr + 1 < rb) {
            wsrc += NI * NO;
            pf0 = *(const float4*)wsrc;
            pf1 = *(const float4*)(wsrc + 4);
        }
        __syncthreads();

        float xq[NI];
#pragma unroll
        for (int i = 0; i < NI; ++i) xq[i] = xsT[i * rbs + rr * 32 + b];

        float tt[NCAPS];
        float Z = 0.f;
        const float* bp2 = &Ws[o * 12];
#pragma unroll
        for (int c = 0; c < NCAPS; ++c) {
            const float* wp = bp2 + c * CSTR;
            const float4 w0 = *(const float4*)wp;
            const float4 w1 = *(const float4*)(wp + 4);
            float uu =      xq[0] * w0.x;
            uu = fmaf(xq[1], w0.y, uu);
            uu = fmaf(xq[2], w0.z, uu);
            uu = fmaf(xq[3], w0.w, uu);
            uu = fmaf(xq[4], w1.x, uu);
            uu = fmaf(xq[5], w1.y, uu);
            uu = fmaf(xq[6], w1.z, uu);
            uu = fmaf(xq[7], w1.w, uu);
            const float ee = exp2f(uu * a2s[c]);
            Z += ee;
            tt[c] = ee * uu;
        }
        const float rz = __builtin_amdgcn_rcpf(Z);
#pragma unroll
        for (int c = 0; c < NCAPS; ++c)
            acc[c] = fmaf(tt[c], rz, acc[c]);
    }

    float* pout = P + (((size_t)blockIdx.x * BATCH + b) * NO + o) * NCAPS;
#pragma unroll
    for (int q = 0; q < NCAPS / 4; ++q) {
        float4 v;
        v.x = acc[4 * q + 0]; v.y = acc[4 * q + 1];
        v.z = acc[4 * q + 2]; v.w = acc[4 * q + 3];
        *(float4*)(pout + 4 * q) = v;
    }
}

__global__ void caps_zero(float* __restrict__ p, int n)
{
    const int i = blockIdx.x * blockDim.x + threadIdx.x;
    if (i < n) p[i] = 0.f;
}

extern "C" void kernel_launch(void* const* d_in, const int* in_sizes, int n_in,
                              void* d_out, int out_size, void* d_ws, size_t ws_size,
                              hipStream_t stream)
{
    const float* x = (const float*)d_in[0];   // [32][4608][8]
    const float* W = (const float*)d_in[1];   // [32][4608][8][16]
    float* out = (float*)d_out;               // [32][32][16]

    float* A  = (float*)d_ws;                 // 16384 floats
    float* P  = A + BATCH * NCAPS * NO;       // NCH * 16384 floats
    float* P2 = P + (size_t)NCH * BATCH * NCAPS * NO;   // 16 * 16384 floats

    const size_t elem = (size_t)BATCH * NCAPS * NO;   // 16384
    caps_zero<<<(int)((elem + 255) / 256), 256, 0, stream>>>(A, (int)elem);

    if ((size_t)(1 + NCH + 16) * elem * sizeof(float) <= ws_size) {
        // Fast path: grid 512 (o-split, 2 blocks/CU), RB=18, 1 barrier per 2 r.
        caps_route_fast<NR / NCH, true><<<2 * NCH, 1024, 0, stream>>>(x, W, A, P);
        caps_partial<<<256, 256, 0, stream>>>(P, P2);
        caps_reduce_squash<<<BATCH * NCAPS, 256, 0, stream>>>(P2, A, nullptr, 16);
        caps_route_fast<NR / NCH, false><<<2 * NCH, 1024, 0, stream>>>(x, W, A, P);
        caps_partial<<<256, 256, 0, stream>>>(P, P2);
        caps_reduce_squash<<<BATCH * NCAPS, 256, 0, stream>>>(P2, A, nullptr, 16);
        caps_route_fast<NR / NCH, false><<<2 * NCH, 1024, 0, stream>>>(x, W, A, P);
        caps_partial<<<256, 256, 0, stream>>>(P, P2);
        caps_reduce_squash<<<BATCH * NCAPS, 256, 0, stream>>>(P2, A, out, 16);
    } else {
        int nchunk = 128;
        while (nchunk > 32 &&
               (size_t)(nchunk + 1) * elem * sizeof(float) > ws_size)
            nchunk >>= 1;
        const int rb = NR / nchunk;
        for (int it = 0; it < 3; ++it) {
            caps_route_generic<<<nchunk, 512, 0, stream>>>(x, W, A, P, rb);
            caps_reduce_squash<<<BATCH * NCAPS, 256, 0, stream>>>(
                P, A, it == 2 ? out : nullptr, nchunk);
        }
    }
}

// Round 14
// 183.687 us; speedup vs baseline: 1.0384x; 1.0384x over previous
//
#include <hip/hip_runtime.h>

#define BATCH 32
#define NCAPS 32
#define NR    4608
#define NI    8
#define NO    16
// Fast-path W tile layout: [slot][i][o], CSTRW = 136 floats (128 + 8 pad).
// 136*4B = 544B rows (16B-aligned); 136 = 8 mod 32 -> slot stride moves start
// bank by 8*(slot&3). Capsule c -> slot (c>>2)+8*(c&3). Read (b64, lanes =
// 8 op2 x 8 co): bank = 8(co&3) + 16(i&1) + 2*op2 -> each 8-lane phase covers
// 16 distinct banks. Staging is LINEAR within a capsule row -> b128 writes,
// conflict-free (phase = 8 q-slots -> banks {0,4,...,28}).
#define CSTRW 136
#define CSTR  200    // generic fallback keeps the R6 layout
#define MAXRB 36
#define NCH   256    // grid 256 (1 block/CU, best measured)
#define L2E   1.44269504088896341f

typedef float f2 __attribute__((ext_vector_type(2)));

// ---------------- fast path ----------------
// 1024 threads; thread = (b-pair bp = t>>6 wave-uniform, c-oct co = bits[5:3],
// o-pair op2 = bits[2:0]). Each thread: 2 b x 4 c x 2 o, with the O-PAIR as the
// packed f2 dimension: W's LDS b64 read {w[i][o],w[i][o+1]} is directly the
// v_pk_fma operand (no broadcast movs), x is splat-hoisted once per r.
// R12's supertile double-buffer (1 barrier per 2 r) and reduce chain retained.
template<int RB, bool FIRST>
__global__ __launch_bounds__(1024, 2) void caps_route_fast(
    const float* __restrict__ x,    // [B][R][I]
    const float* __restrict__ W,    // [C][R][I][O]
    const float* __restrict__ A,    // [B][C][O]
    float* __restrict__ P)          // [NCH][B][C][O]
{
    constexpr int NP = RB / 2;                              // supertiles (9)
    __shared__ __align__(16) float Ws[2][2][NCAPS * CSTRW]; // 69.6 KB
    __shared__ __align__(16) f2    xP[RB][8][2][NI];        // 18.4 KB @ RB=18

    const int t   = threadIdx.x;
    const int op2 = t & 7;            // o-pair: o0 = 2*op2
    const int co  = (t >> 3) & 7;     // c-oct: c = 4*co + cl
    const int bp  = t >> 6;           // wave id = b pair
    const int b0  = 2 * bp;
    const int o0  = 2 * op2;
    const int chunk = blockIdx.x;
    const int r0  = chunk * RB;

    // a2[b][cl] packed over the o-pair, pre-scaled by log2(e).
    f2 a2[2][4];
    if (!FIRST) {
#pragma unroll
        for (int bb = 0; bb < 2; ++bb)
#pragma unroll
            for (int cl = 0; cl < 4; ++cl)
                a2[bb][cl] = *(const f2*)&A[((b0 + bb) * NCAPS + 4 * co + cl) * NO + o0]
                             * L2E;
    }
    f2 acc[2][4];
#pragma unroll
    for (int bb = 0; bb < 2; ++bb)
#pragma unroll
        for (int cl = 0; cl < 4; ++cl) acc[bb][cl] = (f2)0.f;

    // Stage x pre-interleaved by b-pair (R12-proven): xP[rr][j][k][i] = pair 2j+k.
    for (int s = t; s < RB * 16; s += 1024) {
        const int rr = s >> 4, pq = s & 15;
        const float* xp0 = &x[((size_t)(2 * pq + 0) * NR + r0 + rr) * NI];
        const float* xp1 = &x[((size_t)(2 * pq + 1) * NR + r0 + rr) * NI];
        const float4 a0 = *(const float4*)xp0;
        const float4 a1 = *(const float4*)(xp0 + 4);
        const float4 c0 = *(const float4*)xp1;
        const float4 c1 = *(const float4*)(xp1 + 4);
        f2* d = &xP[rr][pq >> 1][pq & 1][0];
        d[0] = f2{a0.x, c0.x}; d[1] = f2{a0.y, c0.y};
        d[2] = f2{a0.z, c0.z}; d[3] = f2{a0.w, c0.w};
        d[4] = f2{a1.x, c1.x}; d[5] = f2{a1.y, c1.y};
        d[6] = f2{a1.z, c1.z}; d[7] = f2{a1.w, c1.w};
    }

    // W staging: capsule row is LINEAR in LDS -> plain b128 copies.
    // Thread owns (c_st = t>>5, sub_r = bit4, q = bits[3:0]): two float4 slots
    // (q*4 and q*4+64) of the 128-float (i,o) block.
    const int c_st  = t >> 5;
    const int sl_st = (c_st >> 2) + 8 * (c_st & 3);
    const int part  = t & 31;
    const int sub_r = part >> 4;
    const int q     = part & 15;
    const int dstf  = sl_st * CSTRW + q * 4;
    const float* wsrc = W + ((size_t)c_st * NR + r0 + sub_r) * (NI * NO) + q * 4;

    // Prologue: stage supertile 0 into buf0; prefetch supertile 1.
    {
        const float4 s0 = *(const float4*)wsrc;
        const float4 s1 = *(const float4*)(wsrc + 64);
        *(float4*)&Ws[0][sub_r][dstf]      = s0;
        *(float4*)&Ws[0][sub_r][dstf + 64] = s1;
    }
    float4 pf0 = {}, pf1 = {};
    if (NP > 1) {
        pf0 = *(const float4*)(wsrc + 256);
        pf1 = *(const float4*)(wsrc + 256 + 64);
    }
    __syncthreads();

    // Per-r compute: capsule 4co+cl at slot co+8cl; thread reads b64 o-pairs.
    auto compute_r = [&](const float* wt, const f2* xv) {
        float xa[NI], xb[NI];
#pragma unroll
        for (int i = 0; i < NI; ++i) { xa[i] = xv[i].x; xb[i] = xv[i].y; }
        f2 u[2][4];
#pragma unroll
        for (int cl = 0; cl < 4; ++cl) {
            const float* wp = wt + (co + 8 * cl) * CSTRW + o0;
            f2 u0 = (f2)0.f, u1 = (f2)0.f;
#pragma unroll
            for (int i = 0; i < NI; ++i) {
                const f2 wv = *(const f2*)(wp + i * 16);
                u0 += wv * xa[i];
                u1 += wv * xb[i];
            }
            u[0][cl] = u0; u[1][cl] = u1;
        }
        if (FIRST) {
            // A == 0 -> softmax uniform: acc += u (1/32 folded into the store).
#pragma unroll
            for (int cl = 0; cl < 4; ++cl) {
                acc[0][cl] += u[0][cl];
                acc[1][cl] += u[1][cl];
            }
        } else {
            f2 Z0 = (f2)0.f, Z1 = (f2)0.f;
#pragma unroll
            for (int cl = 0; cl < 4; ++cl) {
                // logits bounded (|A|<=3, |u|<~15): exp2 safe without max-sub
                // (validated absmax<=2e-3 through R13).
                const f2 l0 = u[0][cl] * a2[0][cl];
                const f2 l1 = u[1][cl] * a2[1][cl];
                f2 e0, e1;
                e0.x = exp2f(l0.x); e0.y = exp2f(l0.y);
                e1.x = exp2f(l1.x); e1.y = exp2f(l1.y);
                Z0 += e0; Z1 += e1;
                u[0][cl] *= e0;     // tt = e * u (reuse u regs)
                u[1][cl] *= e1;
            }
            // Z over 32 c: co lives in lane bits {3,4,5} -> xor 8,16,32.
            Z0.x += __shfl_xor(Z0.x, 8);  Z0.y += __shfl_xor(Z0.y, 8);
            Z1.x += __shfl_xor(Z1.x, 8);  Z1.y += __shfl_xor(Z1.y, 8);
            Z0.x += __shfl_xor(Z0.x, 16); Z0.y += __shfl_xor(Z0.y, 16);
            Z1.x += __shfl_xor(Z1.x, 16); Z1.y += __shfl_xor(Z1.y, 16);
            Z0.x += __shfl_xor(Z0.x, 32); Z0.y += __shfl_xor(Z0.y, 32);
            Z1.x += __shfl_xor(Z1.x, 32); Z1.y += __shfl_xor(Z1.y, 32);
            f2 rz0, rz1;
            rz0.x = __builtin_amdgcn_rcpf(Z0.x); rz0.y = __builtin_amdgcn_rcpf(Z0.y);
            rz1.x = __builtin_amdgcn_rcpf(Z1.x); rz1.y = __builtin_amdgcn_rcpf(Z1.y);
#pragma unroll
            for (int cl = 0; cl < 4; ++cl) {
                acc[0][cl] += u[0][cl] * rz0;
                acc[1][cl] += u[1][cl] * rz1;
            }
        }
    };

#pragma unroll 1
    for (int rp = 0; rp < NP; ++rp) {
        const int cur = rp & 1;
        // Stage next supertile into the other buffer; prefetch rp+2.
        if (rp + 1 < NP) {
            *(float4*)&Ws[cur ^ 1][sub_r][dstf]      = pf0;
            *(float4*)&Ws[cur ^ 1][sub_r][dstf + 64] = pf1;
            if (rp + 2 < NP) {
                pf0 = *(const float4*)(wsrc + (size_t)(rp + 2) * 256);
                pf1 = *(const float4*)(wsrc + (size_t)(rp + 2) * 256 + 64);
            }
        }
        compute_r(&Ws[cur][0][0], &xP[2 * rp + 0][bp >> 1][bp & 1][0]);
        compute_r(&Ws[cur][1][0], &xP[2 * rp + 1][bp >> 1][bp & 1][0]);
        __syncthreads();
    }

    // Epilogue: P[chunk][b][c][o0,o0+1] f2 stores (wave dirties full b-slabs).
#pragma unroll
    for (int bb = 0; bb < 2; ++bb)
#pragma unroll
        for (int cl = 0; cl < 4; ++cl) {
            f2 v = acc[bb][cl];
            if (FIRST) v *= 0.03125f;
            *(f2*)&P[(((size_t)chunk * BATCH + b0 + bb) * NCAPS + 4 * co + cl) * NO + o0] = v;
        }
}

// Stage-1 reduce: coalesced float4 column sums of P[256][16384] -> P2[16][16384].
__global__ __launch_bounds__(256) void caps_partial(const float* __restrict__ P,
                                                    float* __restrict__ P2)
{
    const int tid = threadIdx.x;
    const int ct  = blockIdx.x & 15;
    const int rg  = blockIdx.x >> 4;
    const size_t col = (size_t)ct * 1024 + tid * 4;
    const float* p = P + (size_t)rg * 16 * 16384 + col;
    float4 s = {0.f, 0.f, 0.f, 0.f};
#pragma unroll
    for (int k = 0; k < 16; ++k) {
        const float4 v = *(const float4*)(p + (size_t)k * 16384);
        s.x += v.x; s.y += v.y; s.z += v.z; s.w += v.w;
    }
    *(float4*)(P2 + (size_t)rg * 16384 + col) = s;
}

// Reduce partials over chunks, squash, update A; emit V on the final iteration.
// P layout [chunk][b][c][o].
__global__ void caps_reduce_squash(const float* __restrict__ P,
                                   float* __restrict__ A,
                                   float* __restrict__ out,
                                   int nchunk)
{
    __shared__ float sm[256];
    const int bc  = blockIdx.x;     // b*NCAPS + c
    const int tid = threadIdx.x;    // 256 = 16 j x 16 o
    const int o = tid & 15;
    const int j = tid >> 4;
    float s = 0.f;
    for (int tch = j; tch < nchunk; tch += 16)
        s += P[((size_t)tch * (BATCH * NCAPS) + bc) * NO + o];
    sm[tid] = s;
    __syncthreads();
    if (tid < 16) {
        float S = 0.f;
#pragma unroll
        for (int k = 0; k < 16; ++k) S += sm[tid + 16 * k];
        float sq = S * S;
#pragma unroll
        for (int d = 8; d >= 1; d >>= 1) sq += __shfl_xor(sq, d, 16);
        const float scale = sq / ((1.f + sq) * sqrtf(sq));
        const float V = S * scale;
        const int idx = bc * NO + tid;
        A[idx] += V;
        if (out) out[idx] = V;
    }
}

// ---------------- generic fallback (R6 structure; epilogue -> [b][c][o]) ----------------
__global__ __launch_bounds__(512, 2) void caps_route_generic(
    const float* __restrict__ x, const float* __restrict__ W,
    const float* __restrict__ A, float* __restrict__ P, int rb)
{
    __shared__ __align__(16) float Ws[NCAPS * CSTR];
    __shared__ __align__(16) float xsT[NI * MAXRB * BATCH];

    const int t = threadIdx.x;
    const int b = t & 31;
    const int o = t >> 5;
    const int r0 = blockIdx.x * rb;
    const int rbs = rb * BATCH;

    float a2s[NCAPS];
#pragma unroll
    for (int c = 0; c < NCAPS; ++c)
        a2s[c] = A[(b * NCAPS + c) * NO + o] * L2E;
    float acc[NCAPS];
#pragma unroll
    for (int c = 0; c < NCAPS; ++c) acc[c] = 0.f;

    for (int s = t; s < rbs; s += 512) {
        const int rr = s >> 5, bb = s & 31;
        const float4 v0 = *(const float4*)&x[((size_t)bb * NR + r0 + rr) * NI];
        const float4 v1 = *(const float4*)&x[((size_t)bb * NR + r0 + rr) * NI + 4];
        const float tmp[8] = {v0.x, v0.y, v0.z, v0.w, v1.x, v1.y, v1.z, v1.w};
#pragma unroll
        for (int i = 0; i < NI; ++i) xsT[i * rbs + s] = tmp[i];
    }

    const int cs  = t >> 4;
    const int seg = t & 15;
    const int iw  = seg >> 1;
    const int ob  = (seg & 1) * 8;
    const float* wsrc = W + ((size_t)cs * NR + r0) * (NI * NO) + seg * 8;
    float4 pf0 = *(const float4*)wsrc;
    float4 pf1 = *(const float4*)(wsrc + 4);

    for (int rr = 0; rr < rb; ++rr) {
        __syncthreads();
        {
            const float tmp[8] = {pf0.x, pf0.y, pf0.z, pf0.w,
                                  pf1.x, pf1.y, pf1.z, pf1.w};
#pragma unroll
            for (int k = 0; k < 8; ++k)
                Ws[cs * CSTR + (ob + k) * 12 + iw] = tmp[k];
        }
        if (rr + 1 < rb) {
            wsrc += NI * NO;
            pf0 = *(const float4*)wsrc;
            pf1 = *(const float4*)(wsrc + 4);
        }
        __syncthreads();

        float xq[NI];
#pragma unroll
        for (int i = 0; i < NI; ++i) xq[i] = xsT[i * rbs + rr * 32 + b];

        float tt[NCAPS];
        float Z = 0.f;
        const float* bp2 = &Ws[o * 12];
#pragma unroll
        for (int c = 0; c < NCAPS; ++c) {
            const float* wp = bp2 + c * CSTR;
            const float4 w0 = *(const float4*)wp;
            const float4 w1 = *(const float4*)(wp + 4);
            float uu =      xq[0] * w0.x;
            uu = fmaf(xq[1], w0.y, uu);
            uu = fmaf(xq[2], w0.z, uu);
            uu = fmaf(xq[3], w0.w, uu);
            uu = fmaf(xq[4], w1.x, uu);
            uu = fmaf(xq[5], w1.y, uu);
            uu = fmaf(xq[6], w1.z, uu);
            uu = fmaf(xq[7], w1.w, uu);
            const float ee = exp2f(uu * a2s[c]);
            Z += ee;
            tt[c] = ee * uu;
        }
        const float rz = __builtin_amdgcn_rcpf(Z);
#pragma unroll
        for (int c = 0; c < NCAPS; ++c)
            acc[c] = fmaf(tt[c], rz, acc[c]);
    }

    // [b][c][o] layout to match caps_reduce_squash.
    float* pout = P + (((size_t)blockIdx.x * BATCH + b) * NCAPS) * NO + o;
#pragma unroll
    for (int c = 0; c < NCAPS; ++c) pout[c * NO] = acc[c];
}

__global__ void caps_zero(float* __restrict__ p, int n)
{
    const int i = blockIdx.x * blockDim.x + threadIdx.x;
    if (i < n) p[i] = 0.f;
}

extern "C" void kernel_launch(void* const* d_in, const int* in_sizes, int n_in,
                              void* d_out, int out_size, void* d_ws, size_t ws_size,
                              hipStream_t stream)
{
    const float* x = (const float*)d_in[0];   // [32][4608][8]
    const float* W = (const float*)d_in[1];   // [32][4608][8][16]
    float* out = (float*)d_out;               // [32][32][16]

    float* A  = (float*)d_ws;                 // 16384 floats
    float* P  = A + BATCH * NCAPS * NO;       // NCH * 16384 floats
    float* P2 = P + (size_t)NCH * BATCH * NCAPS * NO;   // 16 * 16384 floats

    const size_t elem = (size_t)BATCH * NCAPS * NO;   // 16384
    caps_zero<<<(int)((elem + 255) / 256), 256, 0, stream>>>(A, (int)elem);

    if ((size_t)(1 + NCH + 16) * elem * sizeof(float) <= ws_size) {
        // Fast path: grid 256 (1 block/CU), RB=18, 1 barrier per 2 r.
        caps_route_fast<NR / NCH, true><<<NCH, 1024, 0, stream>>>(x, W, A, P);
        caps_partial<<<256, 256, 0, stream>>>(P, P2);
        caps_reduce_squash<<<BATCH * NCAPS, 256, 0, stream>>>(P2, A, nullptr, 16);
        caps_route_fast<NR / NCH, false><<<NCH, 1024, 0, stream>>>(x, W, A, P);
        caps_partial<<<256, 256, 0, stream>>>(P, P2);
        caps_reduce_squash<<<BATCH * NCAPS, 256, 0, stream>>>(P2, A, nullptr, 16);
        caps_route_fast<NR / NCH, false><<<NCH, 1024, 0, stream>>>(x, W, A, P);
        caps_partial<<<256, 256, 0, stream>>>(P, P2);
        caps_reduce_squash<<<BATCH * NCAPS, 256, 0, stream>>>(P2, A, out, 16);
    } else {
        int nchunk = 128;
        while (nchunk > 32 &&
               (size_t)(nchunk + 1) * elem * sizeof(float) > ws_size)
            nchunk >>= 1;
        const int rb = NR / nchunk;
        for (int it = 0; it < 3; ++it) {
            caps_route_generic<<<nchunk, 512, 0, stream>>>(x, W, A, P, rb);
            caps_reduce_squash<<<BATCH * NCAPS, 256, 0, stream>>>(
                P, A, it == 2 ? out : nullptr, nchunk);
        }
    }
}

// Round 15
// 152.975 us; speedup vs baseline: 1.2468x; 1.2008x over previous
//
#include <hip/hip_runtime.h>

#define BATCH 32
#define NCAPS 32
#define NR    4608
#define NI    8
#define NO    16
// Fast-path W tile layout: [slot][i][o], CSTRW = 144 floats (128 + 16 pad).
// 144*4B = 576B rows (16B-aligned -> b128 staging writes stay b128).
// 144 = 16 mod 32 and 8*144 = 0 mod 32, capsule c -> slot (c>>2)+8*(c&3):
// b64 READ bank = (16*(co&1) + 2*op2 + 16*i) mod 32. A ds_read_b64 drains
// 16 lanes/phase (16x8B = one 128B sweep): op2 0..7 x co {0,1} covers banks
// {0..15} u {16..31} -- all 32 exactly once. (R14's CSTRW=136 = 8 mod 32 gave
// {0..15} u {8..23}: 8-bank overlap -> 2-way conflict on every W read.)
// b128 STAGING writes drain 8 lanes/phase: q 0..7 -> bank quads {0,4..28}, ok.
#define CSTRW 144
#define CSTR  200    // generic fallback keeps the R6 layout
#define MAXRB 36
#define NCH   256    // grid 256 (1 block/CU, best measured)
#define L2E   1.44269504088896341f

typedef float f2 __attribute__((ext_vector_type(2)));

// ---------------- fast path ----------------
// 1024 threads; thread = (b-pair bp = t>>6 wave-uniform, c-oct co = bits[5:3],
// o-pair op2 = bits[2:0]). Each thread: 2 b x 4 c x 2 o, with the O-PAIR as the
// packed f2 dimension: W's LDS b64 read {w[i][o],w[i][o+1]} is directly the
// v_pk_fma operand (no broadcast movs), x is splat-hoisted once per r.
// R12's supertile double-buffer (1 barrier per 2 r) and reduce chain retained.
template<int RB, bool FIRST>
__global__ __launch_bounds__(1024, 2) void caps_route_fast(
    const float* __restrict__ x,    // [B][R][I]
    const float* __restrict__ W,    // [C][R][I][O]
    const float* __restrict__ A,    // [B][C][O]
    float* __restrict__ P)          // [NCH][B][C][O]
{
    constexpr int NP = RB / 2;                              // supertiles (9)
    __shared__ __align__(16) float Ws[2][2][NCAPS * CSTRW]; // 73.7 KB
    __shared__ __align__(16) f2    xP[RB][8][2][NI];        // 18.4 KB @ RB=18

    const int t   = threadIdx.x;
    const int op2 = t & 7;            // o-pair: o0 = 2*op2
    const int co  = (t >> 3) & 7;     // c-oct: c = 4*co + cl
    const int bp  = t >> 6;           // wave id = b pair
    const int b0  = 2 * bp;
    const int o0  = 2 * op2;
    const int chunk = blockIdx.x;
    const int r0  = chunk * RB;

    // a2[b][cl] packed over the o-pair, pre-scaled by log2(e).
    f2 a2[2][4];
    if (!FIRST) {
#pragma unroll
        for (int bb = 0; bb < 2; ++bb)
#pragma unroll
            for (int cl = 0; cl < 4; ++cl)
                a2[bb][cl] = *(const f2*)&A[((b0 + bb) * NCAPS + 4 * co + cl) * NO + o0]
                             * L2E;
    }
    f2 acc[2][4];
#pragma unroll
    for (int bb = 0; bb < 2; ++bb)
#pragma unroll
        for (int cl = 0; cl < 4; ++cl) acc[bb][cl] = (f2)0.f;

    // Stage x pre-interleaved by b-pair (R12-proven): xP[rr][j][k][i] = pair 2j+k.
    for (int s = t; s < RB * 16; s += 1024) {
        const int rr = s >> 4, pq = s & 15;
        const float* xp0 = &x[((size_t)(2 * pq + 0) * NR + r0 + rr) * NI];
        const float* xp1 = &x[((size_t)(2 * pq + 1) * NR + r0 + rr) * NI];
        const float4 a0 = *(const float4*)xp0;
        const float4 a1 = *(const float4*)(xp0 + 4);
        const float4 c0 = *(const float4*)xp1;
        const float4 c1 = *(const float4*)(xp1 + 4);
        f2* d = &xP[rr][pq >> 1][pq & 1][0];
        d[0] = f2{a0.x, c0.x}; d[1] = f2{a0.y, c0.y};
        d[2] = f2{a0.z, c0.z}; d[3] = f2{a0.w, c0.w};
        d[4] = f2{a1.x, c1.x}; d[5] = f2{a1.y, c1.y};
        d[6] = f2{a1.z, c1.z}; d[7] = f2{a1.w, c1.w};
    }

    // W staging: capsule row is LINEAR in LDS -> plain b128 copies.
    // Thread owns (c_st = t>>5, sub_r = bit4, q = bits[3:0]): two float4 slots
    // (q*4 and q*4+64) of the 128-float (i,o) block.
    const int c_st  = t >> 5;
    const int sl_st = (c_st >> 2) + 8 * (c_st & 3);
    const int part  = t & 31;
    const int sub_r = part >> 4;
    const int q     = part & 15;
    const int dstf  = sl_st * CSTRW + q * 4;
    const float* wsrc = W + ((size_t)c_st * NR + r0 + sub_r) * (NI * NO) + q * 4;

    // Prologue: stage supertile 0 into buf0; prefetch supertile 1.
    {
        const float4 s0 = *(const float4*)wsrc;
        const float4 s1 = *(const float4*)(wsrc + 64);
        *(float4*)&Ws[0][sub_r][dstf]      = s0;
        *(float4*)&Ws[0][sub_r][dstf + 64] = s1;
    }
    float4 pf0 = {}, pf1 = {};
    if (NP > 1) {
        pf0 = *(const float4*)(wsrc + 256);
        pf1 = *(const float4*)(wsrc + 256 + 64);
    }
    __syncthreads();

    // Per-r compute: capsule 4co+cl at slot co+8cl; thread reads b64 o-pairs.
    auto compute_r = [&](const float* wt, const f2* xv) {
        float xa[NI], xb[NI];
#pragma unroll
        for (int i = 0; i < NI; ++i) { xa[i] = xv[i].x; xb[i] = xv[i].y; }
        f2 u[2][4];
#pragma unroll
        for (int cl = 0; cl < 4; ++cl) {
            const float* wp = wt + (co + 8 * cl) * CSTRW + o0;
            f2 u0 = (f2)0.f, u1 = (f2)0.f;
#pragma unroll
            for (int i = 0; i < NI; ++i) {
                const f2 wv = *(const f2*)(wp + i * 16);
                u0 += wv * xa[i];
                u1 += wv * xb[i];
            }
            u[0][cl] = u0; u[1][cl] = u1;
        }
        if (FIRST) {
            // A == 0 -> softmax uniform: acc += u (1/32 folded into the store).
#pragma unroll
            for (int cl = 0; cl < 4; ++cl) {
                acc[0][cl] += u[0][cl];
                acc[1][cl] += u[1][cl];
            }
        } else {
            f2 Z0 = (f2)0.f, Z1 = (f2)0.f;
#pragma unroll
            for (int cl = 0; cl < 4; ++cl) {
                // logits bounded (|A|<=3, |u|<~15): exp2 safe without max-sub
                // (validated absmax<=2e-3 through R14).
                const f2 l0 = u[0][cl] * a2[0][cl];
                const f2 l1 = u[1][cl] * a2[1][cl];
                f2 e0, e1;
                e0.x = exp2f(l0.x); e0.y = exp2f(l0.y);
                e1.x = exp2f(l1.x); e1.y = exp2f(l1.y);
                Z0 += e0; Z1 += e1;
                u[0][cl] *= e0;     // tt = e * u (reuse u regs)
                u[1][cl] *= e1;
            }
            // Z over 32 c: co lives in lane bits {3,4,5} -> xor 8,16,32.
            Z0.x += __shfl_xor(Z0.x, 8);  Z0.y += __shfl_xor(Z0.y, 8);
            Z1.x += __shfl_xor(Z1.x, 8);  Z1.y += __shfl_xor(Z1.y, 8);
            Z0.x += __shfl_xor(Z0.x, 16); Z0.y += __shfl_xor(Z0.y, 16);
            Z1.x += __shfl_xor(Z1.x, 16); Z1.y += __shfl_xor(Z1.y, 16);
            Z0.x += __shfl_xor(Z0.x, 32); Z0.y += __shfl_xor(Z0.y, 32);
            Z1.x += __shfl_xor(Z1.x, 32); Z1.y += __shfl_xor(Z1.y, 32);
            f2 rz0, rz1;
            rz0.x = __builtin_amdgcn_rcpf(Z0.x); rz0.y = __builtin_amdgcn_rcpf(Z0.y);
            rz1.x = __builtin_amdgcn_rcpf(Z1.x); rz1.y = __builtin_amdgcn_rcpf(Z1.y);
#pragma unroll
            for (int cl = 0; cl < 4; ++cl) {
                acc[0][cl] += u[0][cl] * rz0;
                acc[1][cl] += u[1][cl] * rz1;
            }
        }
    };

#pragma unroll 1
    for (int rp = 0; rp < NP; ++rp) {
        const int cur = rp & 1;
        // Stage next supertile into the other buffer; prefetch rp+2.
        if (rp + 1 < NP) {
            *(float4*)&Ws[cur ^ 1][sub_r][dstf]      = pf0;
            *(float4*)&Ws[cur ^ 1][sub_r][dstf + 64] = pf1;
            if (rp + 2 < NP) {
                pf0 = *(const float4*)(wsrc + (size_t)(rp + 2) * 256);
                pf1 = *(const float4*)(wsrc + (size_t)(rp + 2) * 256 + 64);
            }
        }
        compute_r(&Ws[cur][0][0], &xP[2 * rp + 0][bp >> 1][bp & 1][0]);
        compute_r(&Ws[cur][1][0], &xP[2 * rp + 1][bp >> 1][bp & 1][0]);
        __syncthreads();
    }

    // Epilogue: P[chunk][b][c][o0,o0+1] f2 stores (wave dirties full b-slabs).
#pragma unroll
    for (int bb = 0; bb < 2; ++bb)
#pragma unroll
        for (int cl = 0; cl < 4; ++cl) {
            f2 v = acc[bb][cl];
            if (FIRST) v *= 0.03125f;
            *(f2*)&P[(((size_t)chunk * BATCH + b0 + bb) * NCAPS + 4 * co + cl) * NO + o0] = v;
        }
}

// Stage-1 reduce: coalesced float4 column sums of P[256][16384] -> P2[16][16384].
__global__ __launch_bounds__(256) void caps_partial(const float* __restrict__ P,
                                                    float* __restrict__ P2)
{
    const int tid = threadIdx.x;
    const int ct  = blockIdx.x & 15;
    const int rg  = blockIdx.x >> 4;
    const size_t col = (size_t)ct * 1024 + tid * 4;
    const float* p = P + (size_t)rg * 16 * 16384 + col;
    float4 s = {0.f, 0.f, 0.f, 0.f};
#pragma unroll
    for (int k = 0; k < 16; ++k) {
        const float4 v = *(const float4*)(p + (size_t)k * 16384);
        s.x += v.x; s.y += v.y; s.z += v.z; s.w += v.w;
    }
    *(float4*)(P2 + (size_t)rg * 16384 + col) = s;
}

// Reduce partials over chunks, squash, update A; emit V on the final iteration.
// P layout [chunk][b][c][o].
__global__ void caps_reduce_squash(const float* __restrict__ P,
                                   float* __restrict__ A,
                                   float* __restrict__ out,
                                   int nchunk)
{
    __shared__ float sm[256];
    const int bc  = blockIdx.x;     // b*NCAPS + c
    const int tid = threadIdx.x;    // 256 = 16 j x 16 o
    const int o = tid & 15;
    const int j = tid >> 4;
    float s = 0.f;
    for (int tch = j; tch < nchunk; tch += 16)
        s += P[((size_t)tch * (BATCH * NCAPS) + bc) * NO + o];
    sm[tid] = s;
    __syncthreads();
    if (tid < 16) {
        float S = 0.f;
#pragma unroll
        for (int k = 0; k < 16; ++k) S += sm[tid + 16 * k];
        float sq = S * S;
#pragma unroll
        for (int d = 8; d >= 1; d >>= 1) sq += __shfl_xor(sq, d, 16);
        const float scale = sq / ((1.f + sq) * sqrtf(sq));
        const float V = S * scale;
        const int idx = bc * NO + tid;
        A[idx] += V;
        if (out) out[idx] = V;
    }
}

// ---------------- generic fallback (R6 structure; epilogue -> [b][c][o]) ----------------
__global__ __launch_bounds__(512, 2) void caps_route_generic(
    const float* __restrict__ x, const float* __restrict__ W,
    const float* __restrict__ A, float* __restrict__ P, int rb)
{
    __shared__ __align__(16) float Ws[NCAPS * CSTR];
    __shared__ __align__(16) float xsT[NI * MAXRB * BATCH];

    const int t = threadIdx.x;
    const int b = t & 31;
    const int o = t >> 5;
    const int r0 = blockIdx.x * rb;
    const int rbs = rb * BATCH;

    float a2s[NCAPS];
#pragma unroll
    for (int c = 0; c < NCAPS; ++c)
        a2s[c] = A[(b * NCAPS + c) * NO + o] * L2E;
    float acc[NCAPS];
#pragma unroll
    for (int c = 0; c < NCAPS; ++c) acc[c] = 0.f;

    for (int s = t; s < rbs; s += 512) {
        const int rr = s >> 5, bb = s & 31;
        const float4 v0 = *(const float4*)&x[((size_t)bb * NR + r0 + rr) * NI];
        const float4 v1 = *(const float4*)&x[((size_t)bb * NR + r0 + rr) * NI + 4];
        const float tmp[8] = {v0.x, v0.y, v0.z, v0.w, v1.x, v1.y, v1.z, v1.w};
#pragma unroll
        for (int i = 0; i < NI; ++i) xsT[i * rbs + s] = tmp[i];
    }

    const int cs  = t >> 4;
    const int seg = t & 15;
    const int iw  = seg >> 1;
    const int ob  = (seg & 1) * 8;
    const float* wsrc = W + ((size_t)cs * NR + r0) * (NI * NO) + seg * 8;
    float4 pf0 = *(const float4*)wsrc;
    float4 pf1 = *(const float4*)(wsrc + 4);

    for (int rr = 0; rr < rb; ++rr) {
        __syncthreads();
        {
            const float tmp[8] = {pf0.x, pf0.y, pf0.z, pf0.w,
                                  pf1.x, pf1.y, pf1.z, pf1.w};
#pragma unroll
            for (int k = 0; k < 8; ++k)
                Ws[cs * CSTR + (ob + k) * 12 + iw] = tmp[k];
        }
        if (rr + 1 < rb) {
            wsrc += NI * NO;
            pf0 = *(const float4*)wsrc;
            pf1 = *(const float4*)(wsrc + 4);
        }
        __syncthreads();

        float xq[NI];
#pragma unroll
        for (int i = 0; i < NI; ++i) xq[i] = xsT[i * rbs + rr * 32 + b];

        float tt[NCAPS];
        float Z = 0.f;
        const float* bp2 = &Ws[o * 12];
#pragma unroll
        for (int c = 0; c < NCAPS; ++c) {
            const float* wp = bp2 + c * CSTR;
            const float4 w0 = *(const float4*)wp;
            const float4 w1 = *(const float4*)(wp + 4);
            float uu =      xq[0] * w0.x;
            uu = fmaf(xq[1], w0.y, uu);
            uu = fmaf(xq[2], w0.z, uu);
            uu = fmaf(xq[3], w0.w, uu);
            uu = fmaf(xq[4], w1.x, uu);
            uu = fmaf(xq[5], w1.y, uu);
            uu = fmaf(xq[6], w1.z, uu);
            uu = fmaf(xq[7], w1.w, uu);
            const float ee = exp2f(uu * a2s[c]);
            Z += ee;
            tt[c] = ee * uu;
        }
        const float rz = __builtin_amdgcn_rcpf(Z);
#pragma unroll
        for (int c = 0; c < NCAPS; ++c)
            acc[c] = fmaf(tt[c], rz, acc[c]);
    }

    // [b][c][o] layout to match caps_reduce_squash.
    float* pout = P + (((size_t)blockIdx.x * BATCH + b) * NCAPS) * NO + o;
#pragma unroll
    for (int c = 0; c < NCAPS; ++c) pout[c * NO] = acc[c];
}

__global__ void caps_zero(float* __restrict__ p, int n)
{
    const int i = blockIdx.x * blockDim.x + threadIdx.x;
    if (i < n) p[i] = 0.f;
}

extern "C" void kernel_launch(void* const* d_in, const int* in_sizes, int n_in,
                              void* d_out, int out_size, void* d_ws, size_t ws_size,
                              hipStream_t stream)
{
    const float* x = (const float*)d_in[0];   // [32][4608][8]
    const float* W = (const float*)d_in[1];   // [32][4608][8][16]
    float* out = (float*)d_out;               // [32][32][16]

    float* A  = (float*)d_ws;                 // 16384 floats
    float* P  = A + BATCH * NCAPS * NO;       // NCH * 16384 floats
    float* P2 = P + (size_t)NCH * BATCH * NCAPS * NO;   // 16 * 16384 floats

    const size_t elem = (size_t)BATCH * NCAPS * NO;   // 16384
    caps_zero<<<(int)((elem + 255) / 256), 256, 0, stream>>>(A, (int)elem);

    if ((size_t)(1 + NCH + 16) * elem * sizeof(float) <= ws_size) {
        // Fast path: grid 256 (1 block/CU), RB=18, 1 barrier per 2 r.
        caps_route_fast<NR / NCH, true><<<NCH, 1024, 0, stream>>>(x, W, A, P);
        caps_partial<<<256, 256, 0, stream>>>(P, P2);
        caps_reduce_squash<<<BATCH * NCAPS, 256, 0, stream>>>(P2, A, nullptr, 16);
        caps_route_fast<NR / NCH, false><<<NCH, 1024, 0, stream>>>(x, W, A, P);
        caps_partial<<<256, 256, 0, stream>>>(P, P2);
        caps_reduce_squash<<<BATCH * NCAPS, 256, 0, stream>>>(P2, A, nullptr, 16);
        caps_route_fast<NR / NCH, false><<<NCH, 1024, 0, stream>>>(x, W, A, P);
        caps_partial<<<256, 256, 0, stream>>>(P, P2);
        caps_reduce_squash<<<BATCH * NCAPS, 256, 0, stream>>>(P2, A, out, 16);
    } else {
        int nchunk = 128;
        while (nchunk > 32 &&
               (size_t)(nchunk + 1) * elem * sizeof(float) > ws_size)
            nchunk >>= 1;
        const int rb = NR / nchunk;
        for (int it = 0; it < 3; ++it) {
            caps_route_generic<<<nchunk, 512, 0, stream>>>(x, W, A, P, rb);
            caps_reduce_squash<<<BATCH * NCAPS, 256, 0, stream>>>(
                P, A, it == 2 ? out : nullptr, nchunk);
        }
    }
}